// Round 3
// baseline (1208.065 us; speedup 1.0000x reference)
//
#include <hip/hip_runtime.h>

// CPPN fused forward: 12 -> 32 -> 32 -> 32 -> 3, per-node activation select.
// Round 3: weights/biases/act-ids moved to the SCALAR path (s_load from K$)
// — they are wave-uniform, so LDS staging was burning the CU-shared LDS pipe
// (~800 ds_read_b128/wave was ~53% of runtime). Now zero LDS, weights cost
// zero VGPRs, v_fma takes the SGPR operand directly. PIX=1 so the unrolled
// body (~25KB) fits I$ and VGPR stays low for occupancy.

#define BLK 256

constexpr int NIN = 12, HID = 32, NOUT = 3;

__device__ __forceinline__ float tanh_fast(float x) {
    // tanh(x) = 1 - 2/(exp(2x)+1); exact limits at +-inf, ~2e-6 abs error.
    float e = __expf(2.0f * x);
    return 1.0f - 2.0f * __builtin_amdgcn_rcpf(e + 1.0f);
}

__device__ __forceinline__ float apply_act(float x, int id) {
    // id comes from a scalar (uniform) load -> switch is wave-uniform scalar
    // branching, no divergence, no readfirstlane needed.
    switch (id) {
        case 1: return tanh_fast(x);
        case 2: { float e = __expf(-x); return __builtin_amdgcn_rcpf(1.0f + e); }
        case 3: return __sinf(x);
        case 4: return __expf(-0.5f * x * x);
        default: return x;  // 0 = identity
    }
}

// One fully-connected layer, everything unrolled; W/b/a indices are
// compile-time constants -> uniform addresses -> s_load (scalar pipe).
// i outer / j inner so each i reads W[i*NO .. i*NO+31] = 128B contiguous,
// which the compiler merges into s_load_dwordx16 pairs.
template <int NI, int NO>
__device__ __forceinline__ void layer(const float (&hin)[NI], float (&hout)[NO],
                                      const float* __restrict__ W,
                                      const float* __restrict__ b,
                                      const int* __restrict__ a) {
    float acc[NO];
#pragma unroll
    for (int j = 0; j < NO; ++j) acc[j] = b[j];
#pragma unroll
    for (int i = 0; i < NI; ++i) {
        const float h = hin[i];
#pragma unroll
        for (int j = 0; j < NO; ++j) acc[j] = fmaf(h, W[i * NO + j], acc[j]);
    }
#pragma unroll
    for (int j = 0; j < NO; ++j) hout[j] = apply_act(acc[j], a[j]);
}

__global__ void __launch_bounds__(BLK) cppn_kernel(
    const float* __restrict__ xin, const float* __restrict__ bin,
    const float* __restrict__ W1, const float* __restrict__ b1, const int* __restrict__ a1,
    const float* __restrict__ W2, const float* __restrict__ b2, const int* __restrict__ a2,
    const float* __restrict__ W3, const float* __restrict__ b3, const int* __restrict__ a3,
    const float* __restrict__ Wo, const float* __restrict__ bo,
    float* __restrict__ out, int Ppix) {
    const long long px = (long long)blockIdx.x * BLK + threadIdx.x;
    if (px >= Ppix) return;

    float h0[NIN];
    {
        const float4* ip = reinterpret_cast<const float4*>(xin + px * NIN);
        const float4 x0 = ip[0], x1 = ip[1], x2 = ip[2];
        const float xv[NIN] = {x0.x, x0.y, x0.z, x0.w,
                               x1.x, x1.y, x1.z, x1.w,
                               x2.x, x2.y, x2.z, x2.w};
#pragma unroll
        for (int i = 0; i < NIN; ++i) h0[i] = xv[i] + bin[i];  // bin: s_load
    }

    float hA[HID], hB[HID];
    layer<NIN, HID>(h0, hA, W1, b1, a1);
    layer<HID, HID>(hA, hB, W2, b2, a2);
    layer<HID, HID>(hB, hA, W3, b3, a3);

    // output: tanh(h3 @ Wout + bout)
    float o[NOUT];
#pragma unroll
    for (int c = 0; c < NOUT; ++c) {
        float acc = bo[c];
#pragma unroll
        for (int i = 0; i < HID; ++i) acc = fmaf(hA[i], Wo[i * NOUT + c], acc);
        o[c] = tanh_fast(acc);
    }
    out[px * 3 + 0] = o[0];
    out[px * 3 + 1] = o[1];
    out[px * 3 + 2] = o[2];
}

extern "C" void kernel_launch(void* const* d_in, const int* in_sizes, int n_in,
                              void* d_out, int out_size, void* d_ws, size_t ws_size,
                              hipStream_t stream) {
    (void)n_in; (void)out_size; (void)d_ws; (void)ws_size;
    const float* xin = (const float*)d_in[0];
    const float* bin = (const float*)d_in[1];
    const float* W1  = (const float*)d_in[2];
    const float* b1  = (const float*)d_in[3];
    const int*   a1  = (const int*)  d_in[4];
    const float* W2  = (const float*)d_in[5];
    const float* b2  = (const float*)d_in[6];
    const int*   a2  = (const int*)  d_in[7];
    const float* W3  = (const float*)d_in[8];
    const float* b3  = (const float*)d_in[9];
    const int*   a3  = (const int*)  d_in[10];
    const float* Wo  = (const float*)d_in[11];
    const float* bo  = (const float*)d_in[12];
    float* out = (float*)d_out;

    const int Ppix = in_sizes[0] / NIN;
    const int grid = (Ppix + BLK - 1) / BLK;
    hipLaunchKernelGGL(cppn_kernel, dim3(grid), dim3(BLK), 0, stream,
                       xin, bin, W1, b1, a1, W2, b2, a2, W3, b3, a3, Wo, bo,
                       out, Ppix);
}

// Round 4
// 202.178 us; speedup vs baseline: 5.9753x; 5.9753x over previous
//
#include <hip/hip_runtime.h>
#include <hip/hip_bf16.h>

// CPPN via bf16 MFMA (16x16x32), D = W^T @ X orientation.
// - pixel index lives in lane&15 for every layer (no cross-lane movement)
// - layer>=2 k-mapping mu2(q,j)=16*(j>>2)+4q+(j&3) == D residency, so the
//   post-activation values pack directly into the next B fragment
// - all weights/biases/act-ids resident in VGPRs (~80), loaded once per wave,
//   amortized over NT*16 = 256 pixels per wave
// - b1 folded into W1 via a k=12 constant-1.0 input row; b2/b3/bout via C-init

#define BLK 256
#define NT 16  // 16-pixel tiles per wave -> 256 px/wave

constexpr int NIN = 12, HID = 32, NOUT = 3;

typedef __attribute__((ext_vector_type(8))) short short8v;
typedef __attribute__((ext_vector_type(4))) float f32x4;

__device__ __forceinline__ unsigned short f2bf(float f) {
    unsigned u = __builtin_bit_cast(unsigned, f);
    u += 0x7FFFu + ((u >> 16) & 1u);  // RNE
    return (unsigned short)(u >> 16);
}

__device__ __forceinline__ float tanh_fast(float x) {
    float e = __expf(2.0f * x);
    return 1.0f - 2.0f * __builtin_amdgcn_rcpf(e + 1.0f);
}

// 0=identity 1=tanh 2=sigmoid 3=sin 4=gaussian; id is per-lane (VGPR) ->
// branchless select-chain sharing one exp.
__device__ __forceinline__ float act_apply(float x, int id) {
    float e_in = (id == 1) ? (x + x) : ((id == 4) ? (-0.5f * x * x) : -x);
    float e = __expf(e_in);
    float r = __builtin_amdgcn_rcpf(e + 1.0f);
    float res = x;                                   // 0: identity
    res = (id == 1) ? fmaf(-2.0f, r, 1.0f) : res;    // tanh = 1-2/(e^{2x}+1)
    res = (id == 2) ? r : res;                       // sigmoid = 1/(1+e^{-x})
    res = (id == 3) ? __sinf(x) : res;               // sin
    res = (id == 4) ? e : res;                       // gaussian = e^{-x^2/2}
    return res;
}

__global__ void __launch_bounds__(BLK, 4) cppn_mfma(
    const float* __restrict__ xin, const float* __restrict__ bin,
    const float* __restrict__ W1, const float* __restrict__ b1, const int* __restrict__ a1,
    const float* __restrict__ W2, const float* __restrict__ b2, const int* __restrict__ a2,
    const float* __restrict__ W3, const float* __restrict__ b3, const int* __restrict__ a3,
    const float* __restrict__ Wo, const float* __restrict__ bo,
    float* __restrict__ out, int Ppix) {
    const int tid = threadIdx.x;
    const int lane = tid & 63;
    const int wid = tid >> 6;
    const int q = lane >> 4;
    const int l15 = lane & 15;

    // ---- one-time fragment construction (amortized over 256 px) ----
    short8v w1f[2], w2f[2], w3f[2], wof;
#pragma unroll
    for (int t = 0; t < 2; ++t) {
#pragma unroll
        for (int j = 0; j < 8; ++j) {
            // L1 k-mapping mu1(q,j) = 8q+j; row (output node) = 16t + l15
            int k1 = 8 * q + j;
            float v1 = (k1 < NIN) ? W1[k1 * HID + 16 * t + l15]
                     : (k1 == NIN ? b1[16 * t + l15] : 0.0f);
            w1f[t][j] = (short)f2bf(v1);
            // L2/L3 k-mapping mu2(q,j) = 16*(j>>2) + 4q + (j&3)
            int k2 = 16 * (j >> 2) + 4 * q + (j & 3);
            w2f[t][j] = (short)f2bf(W2[k2 * HID + 16 * t + l15]);
            w3f[t][j] = (short)f2bf(W3[k2 * HID + 16 * t + l15]);
        }
    }
#pragma unroll
    for (int j = 0; j < 8; ++j) {
        int k2 = 16 * (j >> 2) + 4 * q + (j & 3);
        wof[j] = (l15 < NOUT) ? (short)f2bf(Wo[k2 * NOUT + l15]) : (short)0;
    }

    f32x4 b2f[2], b3f[2], bof;
#pragma unroll
    for (int t = 0; t < 2; ++t) {
#pragma unroll
        for (int r = 0; r < 4; ++r) {
            b2f[t][r] = b2[16 * t + 4 * q + r];
            b3f[t][r] = b3[16 * t + 4 * q + r];
        }
    }
#pragma unroll
    for (int r = 0; r < 4; ++r) bof[r] = (q == 0 && r < NOUT) ? bo[r] : 0.0f;

    int a1v[8], a2v[8], a3v[8];
#pragma unroll
    for (int e = 0; e < 8; ++e) {
        int j = 16 * (e >> 2) + 4 * q + (e & 3);  // D-layout node index
        a1v[e] = a1[j]; a2v[e] = a2[j]; a3v[e] = a3[j];
    }

    float binv[8];
#pragma unroll
    for (int j = 0; j < 8; ++j) {
        int k = 8 * q + j;
        binv[j] = (k < NIN) ? bin[k] : 0.0f;
    }

    const long long waveIdx = (long long)blockIdx.x * (BLK / 64) + wid;
    const long long px0 = waveIdx * (NT * 16);
    const f32x4 z = {0.0f, 0.0f, 0.0f, 0.0f};

    for (int it = 0; it < NT; ++it) {
        const long long px = px0 + it * 16 + l15;
        const bool ok = (px < Ppix);

        // ---- B0 fragment: k = 8q+j, value x[px][k]+bin[k]; k==12 -> 1.0 ----
        short8v b0f = {0, 0, 0, 0, 0, 0, 0, 0};
        if (q == 0) {
            f32x4 xa = ok ? *reinterpret_cast<const f32x4*>(xin + px * NIN)     : z;
            f32x4 xb = ok ? *reinterpret_cast<const f32x4*>(xin + px * NIN + 4) : z;
#pragma unroll
            for (int j = 0; j < 4; ++j) b0f[j]     = (short)f2bf(xa[j] + binv[j]);
#pragma unroll
            for (int j = 0; j < 4; ++j) b0f[4 + j] = (short)f2bf(xb[j] + binv[4 + j]);
        } else if (q == 1) {
            f32x4 xc = ok ? *reinterpret_cast<const f32x4*>(xin + px * NIN + 8) : z;
#pragma unroll
            for (int j = 0; j < 4; ++j) b0f[j] = (short)f2bf(xc[j] + binv[j]);
            b0f[4] = (short)0x3F80;  // constant-1 bias row (k=12)
        }

        // ---- L1 (bias folded into W1) ----
        f32x4 p0 = __builtin_amdgcn_mfma_f32_16x16x32_bf16(w1f[0], b0f, z, 0, 0, 0);
        f32x4 p1 = __builtin_amdgcn_mfma_f32_16x16x32_bf16(w1f[1], b0f, z, 0, 0, 0);
        short8v hb;
#pragma unroll
        for (int r = 0; r < 4; ++r) hb[r]     = (short)f2bf(act_apply(p0[r], a1v[r]));
#pragma unroll
        for (int r = 0; r < 4; ++r) hb[4 + r] = (short)f2bf(act_apply(p1[r], a1v[4 + r]));

        // ---- L2 ----
        p0 = __builtin_amdgcn_mfma_f32_16x16x32_bf16(w2f[0], hb, b2f[0], 0, 0, 0);
        p1 = __builtin_amdgcn_mfma_f32_16x16x32_bf16(w2f[1], hb, b2f[1], 0, 0, 0);
#pragma unroll
        for (int r = 0; r < 4; ++r) hb[r]     = (short)f2bf(act_apply(p0[r], a2v[r]));
#pragma unroll
        for (int r = 0; r < 4; ++r) hb[4 + r] = (short)f2bf(act_apply(p1[r], a2v[4 + r]));

        // ---- L3 ----
        p0 = __builtin_amdgcn_mfma_f32_16x16x32_bf16(w3f[0], hb, b3f[0], 0, 0, 0);
        p1 = __builtin_amdgcn_mfma_f32_16x16x32_bf16(w3f[1], hb, b3f[1], 0, 0, 0);
#pragma unroll
        for (int r = 0; r < 4; ++r) hb[r]     = (short)f2bf(act_apply(p0[r], a3v[r]));
#pragma unroll
        for (int r = 0; r < 4; ++r) hb[4 + r] = (short)f2bf(act_apply(p1[r], a3v[4 + r]));

        // ---- output layer: rows 0..2 live in q==0, regs 0..2 ----
        f32x4 o = __builtin_amdgcn_mfma_f32_16x16x32_bf16(wof, hb, bof, 0, 0, 0);
        if (q == 0 && ok) {
            out[px * 3 + 0] = tanh_fast(o[0]);
            out[px * 3 + 1] = tanh_fast(o[1]);
            out[px * 3 + 2] = tanh_fast(o[2]);
        }
    }
}

extern "C" void kernel_launch(void* const* d_in, const int* in_sizes, int n_in,
                              void* d_out, int out_size, void* d_ws, size_t ws_size,
                              hipStream_t stream) {
    (void)n_in; (void)out_size; (void)d_ws; (void)ws_size;
    const float* xin = (const float*)d_in[0];
    const float* bin = (const float*)d_in[1];
    const float* W1  = (const float*)d_in[2];
    const float* b1  = (const float*)d_in[3];
    const int*   a1  = (const int*)  d_in[4];
    const float* W2  = (const float*)d_in[5];
    const float* b2  = (const float*)d_in[6];
    const int*   a2  = (const int*)  d_in[7];
    const float* W3  = (const float*)d_in[8];
    const float* b3  = (const float*)d_in[9];
    const int*   a3  = (const int*)  d_in[10];
    const float* Wo  = (const float*)d_in[11];
    const float* bo  = (const float*)d_in[12];
    float* out = (float*)d_out;

    const int Ppix = in_sizes[0] / NIN;
    const int pxPerBlock = (BLK / 64) * NT * 16;  // 1024
    const int grid = (Ppix + pxPerBlock - 1) / pxPerBlock;
    hipLaunchKernelGGL(cppn_mfma, dim3(grid), dim3(BLK), 0, stream,
                       xin, bin, W1, b1, a1, W2, b2, a2, W3, b3, a3, Wo, bo,
                       out, Ppix);
}

// Round 5
// 189.238 us; speedup vs baseline: 6.3838x; 1.0684x over previous
//
#include <hip/hip_runtime.h>
#include <hip/hip_bf16.h>

// CPPN via bf16 MFMA, round 5: wave-uniform activation dispatch.
// Nodes within each hidden layer are permuted (one-time, in-register) so that
// each D-slot's 4-node group shares one activation id -> scalar branch runs
// only the needed 0-5 ops instead of a 20-op branchless chain with always-on
// v_exp + v_sin. Purity is VERIFIED per slot; impure groups use the proven
// per-lane fallback, so the permutation can only affect speed, not output.
// Packing via v_cvt_pk_bf16_f32 (__float22bfloat162_rn). Rolled tile loop.

#define BLK 256
#define NT 16  // 16-pixel tiles per wave -> 256 px/wave

constexpr int NIN = 12, HID = 32, NOUT = 3;

typedef __attribute__((ext_vector_type(8))) short short8v;
typedef __attribute__((ext_vector_type(4))) float f32x4;
typedef __attribute__((ext_vector_type(4))) unsigned uint4v;

__device__ __forceinline__ unsigned short f2bf(float f) {  // setup only
    unsigned u = __builtin_bit_cast(unsigned, f);
    u += 0x7FFFu + ((u >> 16) & 1u);  // RNE
    return (unsigned short)(u >> 16);
}

__device__ __forceinline__ unsigned pk2(float lo, float hi) {
    __hip_bfloat162 h = __float22bfloat162_rn(make_float2(lo, hi));
    unsigned r; __builtin_memcpy(&r, &h, 4);
    return r;
}

__device__ __forceinline__ float tanh_fast(float x) {
    float e = __expf(2.0f * x);
    return 1.0f - 2.0f * __builtin_amdgcn_rcpf(e + 1.0f);
}

// Wave-uniform id (from readlane) -> scalar branches, only needed ops execute.
__device__ __forceinline__ float act_uniform(float x, int sid) {
    if (sid == 0) return x;
    if (sid == 1) return tanh_fast(x);
    if (sid == 2) return __builtin_amdgcn_rcpf(1.0f + __expf(-x));
    if (sid == 3) return __sinf(x);
    return __expf(-0.5f * x * x);  // gaussian
}

// Per-lane fallback (impure slots) — identical formulas to round 4 (proven).
__device__ __forceinline__ float act_lane(float x, int id) {
    float e_in = (id == 1) ? (x + x) : ((id == 4) ? (-0.5f * x * x) : -x);
    float e = __expf(e_in);
    float r = __builtin_amdgcn_rcpf(e + 1.0f);
    float res = x;
    res = (id == 1) ? fmaf(-2.0f, r, 1.0f) : res;
    res = (id == 2) ? r : res;
    res = (id == 3) ? __sinf(x) : res;
    res = (id == 4) ? e : res;
    return res;
}

template <bool GUARD>
__global__ void __launch_bounds__(BLK, 4) cppn_mfma(
    const float* __restrict__ xin, const float* __restrict__ bin,
    const float* __restrict__ W1, const float* __restrict__ b1, const int* __restrict__ a1,
    const float* __restrict__ W2, const float* __restrict__ b2, const int* __restrict__ a2,
    const float* __restrict__ W3, const float* __restrict__ b3, const int* __restrict__ a3,
    const float* __restrict__ Wo, const float* __restrict__ bo,
    float* __restrict__ out, int Ppix, int pxBase) {
    const int tid = threadIdx.x;
    const int lane = tid & 63;
    const int wid = tid >> 6;
    const int q = lane >> 4;
    const int l15 = lane & 15;
    const int n = lane & 31;

    // ---- build node permutation per layer: sort by act id, scrambled so each
    // slot group {16t+4q+o} maps to 4 consecutive sorted positions ----
    auto build_perm = [&](const int* __restrict__ a) -> int {
        int myid = a[n];
        unsigned m0 = (unsigned)__ballot(myid == 0);
        unsigned m1 = (unsigned)__ballot(myid == 1);
        unsigned m2 = (unsigned)__ballot(myid == 2);
        unsigned m3 = (unsigned)__ballot(myid == 3);
        unsigned m4 = (unsigned)__ballot(myid == 4);
        int c0 = __popc(m0), c1 = __popc(m1), c2 = __popc(m2), c3 = __popc(m3);
        int pre = 0;
        pre = (myid == 1) ? c0 : pre;
        pre = (myid == 2) ? c0 + c1 : pre;
        pre = (myid == 3) ? c0 + c1 + c2 : pre;
        pre = (myid == 4) ? c0 + c1 + c2 + c3 : pre;
        unsigned mm = m0;
        mm = (myid == 1) ? m1 : mm;
        mm = (myid == 2) ? m2 : mm;
        mm = (myid == 3) ? m3 : mm;
        mm = (myid == 4) ? m4 : mm;
        unsigned lt = (1u << n) - 1u;
        int pos = pre + __popc(mm & lt);  // stable rank, bijective 0..31
        // sorted position -> new index: t=pos>>4, q'=pos&3, o=(pos>>2)&3
        int npr = ((pos >> 4) << 4) + ((pos & 3) << 2) + ((pos >> 2) & 3);
        int perm = __builtin_amdgcn_ds_permute(npr << 2, n);  // perm[new]=orig
        return perm & 31;
    };
    const int perm1 = build_perm(a1);
    const int perm2 = build_perm(a2);
    const int perm3 = build_perm(a3);

    auto pat = [&](int permv, int idx) -> int {  // perm[idx], any lane
        return __builtin_amdgcn_ds_bpermute(idx << 2, permv) & 31;
    };

    // ---- fragment construction (one-time) ----
    int o1[2], o2[2], o3[2];
#pragma unroll
    for (int t = 0; t < 2; ++t) {
        o1[t] = pat(perm1, 16 * t + l15);
        o2[t] = pat(perm2, 16 * t + l15);
        o3[t] = pat(perm3, 16 * t + l15);
    }
    int i2v[8], i3v[8], iov[8];
#pragma unroll
    for (int j = 0; j < 8; ++j) {
        int kk = 16 * (j >> 2) + 4 * q + (j & 3);  // mu2 k-slot mapping
        i2v[j] = pat(perm1, kk);
        i3v[j] = pat(perm2, kk);
        iov[j] = pat(perm3, kk);
    }
    short8v w1f[2], w2f[2], w3f[2], wof;
#pragma unroll
    for (int t = 0; t < 2; ++t) {
#pragma unroll
        for (int j = 0; j < 8; ++j) {
            int k1 = 8 * q + j;  // mu1: inputs unpermuted
            float v1 = (k1 < NIN) ? W1[k1 * HID + o1[t]]
                     : (k1 == NIN ? b1[o1[t]] : 0.0f);
            w1f[t][j] = (short)f2bf(v1);
            w2f[t][j] = (short)f2bf(W2[i2v[j] * HID + o2[t]]);
            w3f[t][j] = (short)f2bf(W3[i3v[j] * HID + o3[t]]);
        }
    }
#pragma unroll
    for (int j = 0; j < 8; ++j)
        wof[j] = (l15 < NOUT) ? (short)f2bf(Wo[iov[j] * NOUT + l15]) : (short)0;

    f32x4 b2f[2], b3f[2], bof;
    unsigned av1 = 0, av2 = 0, av3 = 0;  // per-lane 4-bit act ids (fallback)
#pragma unroll
    for (int e = 0; e < 8; ++e) {
        int t = e >> 2, r = e & 3;
        int idx = 16 * t + 4 * q + r;  // D-slot new-node index
        int p1i = pat(perm1, idx), p2i = pat(perm2, idx), p3i = pat(perm3, idx);
        b2f[t][r] = b2[p2i];
        b3f[t][r] = b3[p3i];
        av1 |= (unsigned)(a1[p1i] & 15) << (4 * e);
        av2 |= (unsigned)(a2[p2i] & 15) << (4 * e);
        av3 |= (unsigned)(a3[p3i] & 15) << (4 * e);
    }
#pragma unroll
    for (int r = 0; r < 4; ++r) bof[r] = (q == 0 && r < NOUT) ? bo[r] : 0.0f;

    // ---- per-slot uniform id + purity (verified, not assumed) ----
    int idn1 = a1[perm1], idn2 = a2[perm2], idn3 = a3[perm3];
    unsigned sidw1 = 0, sidw2 = 0, sidw3 = 0, prw1 = 0, prw2 = 0, prw3 = 0;
#pragma unroll
    for (int e = 0; e < 8; ++e) {
        int g = 16 * (e >> 2) + (e & 3);
        {
            int s0 = __builtin_amdgcn_readlane(idn1, g);
            int s1 = __builtin_amdgcn_readlane(idn1, g + 4);
            int s2 = __builtin_amdgcn_readlane(idn1, g + 8);
            int s3 = __builtin_amdgcn_readlane(idn1, g + 12);
            sidw1 |= (unsigned)(s0 & 15) << (4 * e);
            prw1 |= (unsigned)((s0 == s1) & (s0 == s2) & (s0 == s3)) << e;
        }
        {
            int s0 = __builtin_amdgcn_readlane(idn2, g);
            int s1 = __builtin_amdgcn_readlane(idn2, g + 4);
            int s2 = __builtin_amdgcn_readlane(idn2, g + 8);
            int s3 = __builtin_amdgcn_readlane(idn2, g + 12);
            sidw2 |= (unsigned)(s0 & 15) << (4 * e);
            prw2 |= (unsigned)((s0 == s1) & (s0 == s2) & (s0 == s3)) << e;
        }
        {
            int s0 = __builtin_amdgcn_readlane(idn3, g);
            int s1 = __builtin_amdgcn_readlane(idn3, g + 4);
            int s2 = __builtin_amdgcn_readlane(idn3, g + 8);
            int s3 = __builtin_amdgcn_readlane(idn3, g + 12);
            sidw3 |= (unsigned)(s0 & 15) << (4 * e);
            prw3 |= (unsigned)((s0 == s1) & (s0 == s2) & (s0 == s3)) << e;
        }
    }

    auto actpack = [&](f32x4 p0, f32x4 p1, unsigned sidw, unsigned prw,
                       unsigned av) -> uint4v {
        float h[8];
#pragma unroll
        for (int e = 0; e < 8; ++e) {
            float x = (e < 4) ? p0[e] : p1[e - 4];
            int sid = (int)((sidw >> (4 * e)) & 15u);
            if ((prw >> e) & 1u) h[e] = act_uniform(x, sid);       // uniform: scalar branch
            else                 h[e] = act_lane(x, (int)((av >> (4 * e)) & 15u));
        }
        uint4v w;
        w[0] = pk2(h[0], h[1]); w[1] = pk2(h[2], h[3]);
        w[2] = pk2(h[4], h[5]); w[3] = pk2(h[6], h[7]);
        return w;
    };

    float binv[8];
#pragma unroll
    for (int j = 0; j < 8; ++j) {
        int k = 8 * q + j;
        binv[j] = (k < NIN) ? bin[k] : 0.0f;
    }

    const long long wIdx = (long long)blockIdx.x * (BLK / 64) + wid;
    const long long px0 = (long long)pxBase + wIdx * (NT * 16);
    const float* __restrict__ xbase = xin + px0 * NIN;
    float* __restrict__ obase = out + px0 * 3;
    const f32x4 z = {0.0f, 0.0f, 0.0f, 0.0f};

#pragma unroll 1
    for (int it = 0; it < NT; ++it) {
        const int po = it * 16 + l15;
        const bool ok = !GUARD || (px0 + po < (long long)Ppix);

        uint4v b0w = {0, 0, 0, 0};
        if (q == 0) {
            if (ok) {
                const float4* ip = reinterpret_cast<const float4*>(xbase + po * NIN);
                float4 xa = ip[0], xb = ip[1];
                b0w[0] = pk2(xa.x + binv[0], xa.y + binv[1]);
                b0w[1] = pk2(xa.z + binv[2], xa.w + binv[3]);
                b0w[2] = pk2(xb.x + binv[4], xb.y + binv[5]);
                b0w[3] = pk2(xb.z + binv[6], xb.w + binv[7]);
            }
        } else if (q == 1) {
            if (ok) {
                float4 xc = reinterpret_cast<const float4*>(xbase + po * NIN)[2];
                b0w[0] = pk2(xc.x + binv[0], xc.y + binv[1]);
                b0w[1] = pk2(xc.z + binv[2], xc.w + binv[3]);
            }
            b0w[2] = 0x3F80u;  // constant-1 bias row (k=12), bf16(1.0) low half
        }

        short8v hb = __builtin_bit_cast(short8v, b0w);
        f32x4 p0 = __builtin_amdgcn_mfma_f32_16x16x32_bf16(w1f[0], hb, z, 0, 0, 0);
        f32x4 p1 = __builtin_amdgcn_mfma_f32_16x16x32_bf16(w1f[1], hb, z, 0, 0, 0);

        hb = __builtin_bit_cast(short8v, actpack(p0, p1, sidw1, prw1, av1));
        p0 = __builtin_amdgcn_mfma_f32_16x16x32_bf16(w2f[0], hb, b2f[0], 0, 0, 0);
        p1 = __builtin_amdgcn_mfma_f32_16x16x32_bf16(w2f[1], hb, b2f[1], 0, 0, 0);

        hb = __builtin_bit_cast(short8v, actpack(p0, p1, sidw2, prw2, av2));
        p0 = __builtin_amdgcn_mfma_f32_16x16x32_bf16(w3f[0], hb, b3f[0], 0, 0, 0);
        p1 = __builtin_amdgcn_mfma_f32_16x16x32_bf16(w3f[1], hb, b3f[1], 0, 0, 0);

        hb = __builtin_bit_cast(short8v, actpack(p0, p1, sidw3, prw3, av3));
        f32x4 o4 = __builtin_amdgcn_mfma_f32_16x16x32_bf16(wof, hb, bof, 0, 0, 0);

        if (q == 0 && ok) {
            float* op = obase + po * 3;
            op[0] = tanh_fast(o4[0]);
            op[1] = tanh_fast(o4[1]);
            op[2] = tanh_fast(o4[2]);
        }
    }
}

extern "C" void kernel_launch(void* const* d_in, const int* in_sizes, int n_in,
                              void* d_out, int out_size, void* d_ws, size_t ws_size,
                              hipStream_t stream) {
    (void)n_in; (void)out_size; (void)d_ws; (void)ws_size;
    const float* xin = (const float*)d_in[0];
    const float* bin = (const float*)d_in[1];
    const float* W1  = (const float*)d_in[2];
    const float* b1  = (const float*)d_in[3];
    const int*   a1  = (const int*)  d_in[4];
    const float* W2  = (const float*)d_in[5];
    const float* b2  = (const float*)d_in[6];
    const int*   a2  = (const int*)  d_in[7];
    const float* W3  = (const float*)d_in[8];
    const float* b3  = (const float*)d_in[9];
    const int*   a3  = (const int*)  d_in[10];
    const float* Wo  = (const float*)d_in[11];
    const float* bo  = (const float*)d_in[12];
    float* out = (float*)d_out;

    const int Ppix = in_sizes[0] / NIN;
    const int pxPerBlock = (BLK / 64) * NT * 16;  // 1024
    const int fullBlocks = Ppix / pxPerBlock;
    const int rem = Ppix - fullBlocks * pxPerBlock;
    if (fullBlocks > 0)
        hipLaunchKernelGGL((cppn_mfma<false>), dim3(fullBlocks), dim3(BLK), 0, stream,
                           xin, bin, W1, b1, a1, W2, b2, a2, W3, b3, a3, Wo, bo,
                           out, Ppix, 0);
    if (rem > 0)
        hipLaunchKernelGGL((cppn_mfma<true>), dim3(1), dim3(BLK), 0, stream,
                           xin, bin, W1, b1, a1, W2, b2, a2, W3, b3, a3, Wo, bo,
                           out, Ppix, fullBlocks * pxPerBlock);
}